// Round 2
// baseline (665.567 us; speedup 1.0000x reference)
//
#include <hip/hip_runtime.h>
#include <math.h>

#define BB 32
#define TT 2048
#define VV 1024
#define SS 256
#define LSTRIDE 260   // per-t row in G: tokens j=0..255, blank at 256, pad to 260 (16B-aligned)
#define TCHUNK 4

// Kernel A: G[b][t][j] = (j < Sl[b]) ? exp(lp[b][t][tok[b][j]]) : 0 ; G[b][t][256] = exp(lp[b][t][0])
__global__ __launch_bounds__(256) void ctc_pre(const float* __restrict__ lp,
    const int* __restrict__ tokens, const int* __restrict__ cqt,
    const int* __restrict__ slen, float* __restrict__ G, float* __restrict__ out)
{
    __shared__ float row[VV];
    __shared__ int   toks[SS];
    const int tid = threadIdx.x;
    const int bx  = blockIdx.x;
    if (bx == 0 && tid == 0) out[0] = 0.f;   // zero the atomic accumulator (d_out is poisoned)
    const int nchunk = TT / TCHUNK;
    const int b  = bx / nchunk;
    const int t0 = (bx % nchunk) * TCHUNK;
    const int Tl = cqt[b];
    if (t0 >= Tl) return;                    // rows t>=Tl never read by walker
    const int Sl = slen[b];
    toks[tid] = tokens[b * SS + tid];
    __syncthreads();
    for (int k = 0; k < TCHUNK; ++k) {
        const int t = t0 + k;
        if (t >= Tl) break;                  // uniform across block
        const float4* rp = (const float4*)(lp + ((size_t)b * TT + t) * VV);
        ((float4*)row)[tid] = rp[tid];       // stage full 4KB row, coalesced
        __syncthreads();
        float* gp = G + ((size_t)b * TT + t) * LSTRIDE;
        gp[tid] = (tid < Sl) ? __expf(row[toks[tid]]) : 0.f;
        if (tid == 0) gp[256] = __expf(row[0]);
        __syncthreads();
    }
}

// Kernel B: serial CTC forward in linear domain, one wave per sample.
// Thread i owns states 8i..8i+7 (pairs j=4i..4i+3: even=blank, odd=token j).
// Each lane keeps its OWN power-of-2 exponent Etot (true = stored * 2^Etot);
// lane-local spread of 8 adjacent alpha states is ~25-30 nats << fp32 band,
// while the global spread (~200 nats) lives in the per-lane exponents.
__global__ __launch_bounds__(64) void ctc_walk(const float* __restrict__ G,
    const int* __restrict__ tokens, const int* __restrict__ cqt,
    const int* __restrict__ slen, float* __restrict__ out)
{
    const int b    = blockIdx.x;
    const int lane = threadIdx.x;
    const int Tl   = cqt[b];
    const int Sl   = slen[b];
    const float* __restrict__ Gb = G + (size_t)b * TT * LSTRIDE;
    const int j0 = lane * 4;
    const int* tb = tokens + b * SS;
    // rep_ok for this thread's 4 odd states: tok[j] != tok[j-1] (j==0: ext_m2=0 -> always ok)
    const int tm1 = (j0 == 0) ? 0 : tb[j0 - 1];
    const int q0 = tb[j0], q1 = tb[j0 + 1], q2 = tb[j0 + 2], q3 = tb[j0 + 3];
    const float m0 = (q0 != tm1) ? 1.f : 0.f;
    const float m1 = (q1 != q0)  ? 1.f : 0.f;
    const float m2 = (q2 != q1)  ? 1.f : 0.f;
    const float m3 = (q3 != q2)  ? 1.f : 0.f;
    const float lzm = (lane == 0) ? 0.f : 1.f;   // lane 0's halo = -inf (0 linear)

    float a0=0.f,a1=0.f,a2=0.f,a3=0.f,a4=0.f,a5=0.f,a6=0.f,a7=0.f,aX=0.f; // aX = state 512 (lane 63)
    {   // t=0 init: alpha[0]=exp(lp[0][blank]), alpha[1]=exp(lp[0][tok0])
        const float pb0 = Gb[256];
        const float pe0 = Gb[0];
        if (lane == 0) { a0 = pb0; a1 = pe0; }
    }
    int   Etot = 0;      // per-lane: true = stored * 2^Etot
    float sfac = lzm;    // halo scale: 2^(E_prevlane - E_mine), 0 on lane 0

    float4 peA[8], peB[8];
    float  pbA[8], pbB[8];

#define LOADC(tc, PE, PB) do { \
    _Pragma("unroll") \
    for (int k = 0; k < 8; ++k) { \
        int tt = (tc) + k; tt = (tt < Tl) ? tt : (Tl - 1); \
        const float* gp = Gb + (size_t)tt * LSTRIDE; \
        PE[k] = *(const float4*)(gp + j0); \
        PB[k] = gp[256]; \
    } } while (0)

#define ONESTEP(pe4, pbv) do { \
    const float h1 = __shfl_up(a7, 1) * sfac;              /* alpha[8i-1] (old), rescaled */ \
    const float pb_ = (pbv); \
    const float n0 = pb_ * (a0 + h1); \
    const float n1 = (pe4).x * (a1 + a0 + m0 * h1); \
    const float n2 = pb_ * (a2 + a1); \
    const float n3 = (pe4).y * (a3 + a2 + m1 * a1); \
    const float n4 = pb_ * (a4 + a3); \
    const float n5 = (pe4).z * (a5 + a4 + m2 * a3); \
    const float n6 = pb_ * (a6 + a5); \
    const float n7 = (pe4).w * (a7 + a6 + m3 * a5); \
    aX = pb_ * (aX + a7); \
    a0=n0;a1=n1;a2=n2;a3=n3;a4=n4;a5=n5;a6=n6;a7=n7; \
} while (0)

// Lane-local renorm: rescale own 9 regs to mantissa band, update own Etot,
// re-derive halo scale factor. Zero lanes adopt the left neighbor's exponent
// so the seeding halo always arrives with sfac == 1 (exact).
#define RENORM_LOCAL() do { \
    float mm = fmaxf(fmaxf(fmaxf(a0,a1),fmaxf(a2,a3)), fmaxf(fmaxf(a4,a5),fmaxf(a6,a7))); \
    mm = fmaxf(mm, aX); \
    int ee = 0; \
    if (mm > 0.f) { (void)frexpf(mm, &ee); } \
    const float sc = ldexpf(1.f, -ee);   /* exact power-of-2 scaling */ \
    a0*=sc;a1*=sc;a2*=sc;a3*=sc;a4*=sc;a5*=sc;a6*=sc;a7*=sc;aX*=sc; \
    Etot += ee; \
    const int Ep = __shfl_up(Etot, 1); \
    if (mm == 0.f && lane > 0) Etot = Ep; \
    int dd = Ep - Etot; \
    dd = (dd < -126) ? -126 : ((dd > 100) ? 100 : dd); \
    sfac = ldexpf(lzm, dd); \
} while (0)

#define STEPS(PE, PB, nv) do { \
    _Pragma("unroll") \
    for (int k = 0; k < 8; ++k) { \
        if (k < (nv)) ONESTEP(PE[k], PB[k]); \
        if (k == 3 || k == 7) RENORM_LOCAL(); \
    } } while (0)

    LOADC(1, peA, pbA);
    int t = 1;
    for (;;) {
        {
            const bool more = (t + 8) < Tl;
            int nv = Tl - t; nv = (nv > 8) ? 8 : nv;
            if (more) LOADC(t + 8, peB, pbB);   // prefetch next chunk while computing this one
            STEPS(peA, pbA, nv);
            t += 8;
            if (!more) break;
        }
        {
            const bool more = (t + 8) < Tl;
            int nv = Tl - t; nv = (nv > 8) ? 8 : nv;
            if (more) LOADC(t + 8, peA, pbA);
            STEPS(peB, pbB, nv);
            t += 8;
            if (!more) break;
        }
    }

    __shared__ float als[513];
    __shared__ int   aE[65];
    als[8 * lane + 0] = a0; als[8 * lane + 1] = a1;
    als[8 * lane + 2] = a2; als[8 * lane + 3] = a3;
    als[8 * lane + 4] = a4; als[8 * lane + 5] = a5;
    als[8 * lane + 6] = a6; als[8 * lane + 7] = a7;
    aE[lane] = Etot;
    if (lane == 63) { als[512] = aX; aE[64] = Etot; }
    __syncthreads();
    if (lane == 0) {
        const int sA = 2 * Sl, sB = 2 * Sl - 1;
        const float vA = als[sA], vB = als[sB];
        const int   eA = aE[sA >> 3], eB = aE[sB >> 3];
        int em;
        if (vA > 0.f && vB > 0.f) em = (eA > eB) ? eA : eB;
        else if (vA > 0.f)        em = eA;
        else if (vB > 0.f)        em = eB;
        else                      em = 0;
        const double s = ldexp((double)vA, eA - em) + ldexp((double)vB, eB - em);
        double loss = -(log(s) + (double)em * 0.6931471805599453);
        if (!(loss < 1e29)) loss = 0.0;       // matches ref where(losses>1e29, 0); also NaN/inf-safe
        atomicAdd(out, (float)(loss / ((double)Sl * (double)BB)));
    }
#undef LOADC
#undef ONESTEP
#undef STEPS
#undef RENORM_LOCAL
}

extern "C" void kernel_launch(void* const* d_in, const int* in_sizes, int n_in,
                              void* d_out, int out_size, void* d_ws, size_t ws_size,
                              hipStream_t stream)
{
    const float* lp     = (const float*)d_in[0];
    const int*   tokens = (const int*)d_in[1];
    const int*   cqt    = (const int*)d_in[2];
    const int*   slen   = (const int*)d_in[3];
    float* out = (float*)d_out;
    float* G   = (float*)d_ws;   // needs B*T*260*4 = 68.2 MB of workspace

    hipLaunchKernelGGL(ctc_pre,  dim3(BB * (TT / TCHUNK)), dim3(256), 0, stream,
                       lp, tokens, cqt, slen, G, out);
    hipLaunchKernelGGL(ctc_walk, dim3(BB), dim3(64), 0, stream,
                       G, tokens, cqt, slen, out);
}

// Round 3
// 633.955 us; speedup vs baseline: 1.0499x; 1.0499x over previous
//
#include <hip/hip_runtime.h>
#include <math.h>

#define BB 32
#define TT 2048
#define VV 1024
#define SS 256
#define TCHUNK 4

// ---- helpers: async global->LDS (compiler cannot sink/defeat these) ----
__device__ __forceinline__ void async_ld16(const float* g, const float* l) {
    __builtin_amdgcn_global_load_lds(
        (const __attribute__((address_space(1))) void*)(uintptr_t)g,
        (__attribute__((address_space(3))) void*)(unsigned)(uintptr_t)l, 16, 0, 0);
}
__device__ __forceinline__ void async_ld4(const float* g, const float* l) {
    __builtin_amdgcn_global_load_lds(
        (const __attribute__((address_space(1))) void*)(uintptr_t)g,
        (__attribute__((address_space(3))) void*)(unsigned)(uintptr_t)l, 4, 0, 0);
}
// s_waitcnt simm16: [3:0]=vmcnt lo, [6:4]=expcnt, [11:8]=lgkmcnt, [15:14]=vmcnt hi
#define WAIT_VM27() __builtin_amdgcn_s_waitcnt(0x4F7B)  // vmcnt<=27, others unconstrained
#define WAIT_VM0()  __builtin_amdgcn_s_waitcnt(0x0F70)  // vmcnt<=0

// Kernel A: G[b][t][j] = (j<Sl)? exp(lp[b][t][tok_j]) : 0  (row = 256 floats = 64 lanes x 16B)
//           Gbl[b][t]  = exp(lp[b][t][0])  (blank)
__global__ __launch_bounds__(256) void ctc_pre(const float* __restrict__ lp,
    const int* __restrict__ tokens, const int* __restrict__ cqt,
    const int* __restrict__ slen, float* __restrict__ G, float* __restrict__ Gbl,
    float* __restrict__ out)
{
    __shared__ __align__(16) float rows[TCHUNK][VV];
    __shared__ int toks[SS];
    const int tid = threadIdx.x;
    const int bx  = blockIdx.x;
    if (bx == 0 && tid == 0) out[0] = 0.f;   // zero the atomic accumulator (d_out is poisoned)
    const int nchunk = TT / TCHUNK;
    const int b  = bx / nchunk;
    const int t0 = (bx % nchunk) * TCHUNK;
    const int Tl = cqt[b];
    if (t0 >= Tl) return;                    // rows t>=Tl never read by walker
    const int Sl = slen[b];
    toks[tid] = tokens[b * SS + tid];
#pragma unroll
    for (int k = 0; k < TCHUNK; ++k) {       // stage up to 4 rows, one barrier total
        const int t = t0 + k;
        if (t < Tl)
            ((float4*)rows[k])[tid] = ((const float4*)(lp + ((size_t)b * TT + t) * VV))[tid];
    }
    __syncthreads();
#pragma unroll
    for (int k = 0; k < TCHUNK; ++k) {
        const int t = t0 + k;
        if (t >= Tl) break;                  // uniform across block
        float* gp = G + ((size_t)b * TT + t) * 256;
        gp[tid] = (tid < Sl) ? __expf(rows[k][toks[tid]]) : 0.f;
        if (tid == 0) Gbl[b * TT + t] = __expf(rows[k][0]);
    }
}

// Kernel B: serial CTC forward in linear domain, one wave per sample.
// Thread i owns states 8i..8i+7 (pairs j=4i..4i+3: even=blank, odd=token j).
// Per-lane power-of-2 exponent Etot (true = stored * 2^Etot); halo a7 crosses
// lanes via one shfl/step, rescaled by sfac = 2^(E_left - E_mine).
// Memory: 4-slot LDS ring filled by async global_load_lds, prefetch depth 3,
// consumed behind explicit s_waitcnt vmcnt(27) (9 vm-ops per chunk in flight x3).
__global__ __launch_bounds__(64) void ctc_walk(const float* __restrict__ G,
    const float* __restrict__ Gbl, const int* __restrict__ tokens,
    const int* __restrict__ cqt, const int* __restrict__ slen, float* __restrict__ out)
{
    __shared__ __align__(16) float tokL[4][8 * 256];   // 32 KB: 4 slots x 8 rows x 1KB
    __shared__ __align__(16) float blkL[4][64];        // 1 KB: blank windows
    __shared__ float als[513];
    __shared__ int   aE[65];

    const int b    = blockIdx.x;
    const int lane = threadIdx.x;
    const int Tl   = cqt[b];
    const int Sl   = slen[b];
    const float* __restrict__ Gb   = G   + (size_t)b * TT * 256;
    const float* __restrict__ GblB = Gbl + (size_t)b * TT;
    const int j0 = lane * 4;
    const int* tb = tokens + b * SS;
    const int tm1 = (j0 == 0) ? 0 : tb[j0 - 1];
    const int q0 = tb[j0], q1 = tb[j0 + 1], q2 = tb[j0 + 2], q3 = tb[j0 + 3];
    const float m0 = (q0 != tm1) ? 1.f : 0.f;
    const float m1 = (q1 != q0)  ? 1.f : 0.f;
    const float m2 = (q2 != q1)  ? 1.f : 0.f;
    const float m3 = (q3 != q2)  ? 1.f : 0.f;
    const float lzm = (lane == 0) ? 0.f : 1.f;

    float a0=0.f,a1=0.f,a2=0.f,a3=0.f,a4=0.f,a5=0.f,a6=0.f,a7=0.f,aX=0.f;
    if (lane == 0) { a0 = GblB[0]; a1 = Gb[0]; }   // t=0 init
    int   Etot = 0;
    float sfac = lzm;

    // Issue one chunk (8 token rows, clamped, + one 64-wide blank window) = 9 vm ops
#define ISSUE(slot, tbase) do { \
    const float* lt = tokL[slot]; \
    _Pragma("unroll") \
    for (int k = 0; k < 8; ++k) { \
        int tt = (tbase) + k; tt = (tt < Tl) ? tt : (Tl - 1); \
        async_ld16(Gb + (size_t)tt * 256, lt + k * 256); \
    } \
    async_ld4(GblB + (tbase), blkL[slot]); \
} while (0)

#define ONESTEP(tcur, bcur, k) do { \
    const float4 pe4 = *(const float4*)((tcur) + ((k) << 8) + (lane << 2)); \
    const float pb_ = (bcur)[k]; \
    const float h1 = __shfl_up(a7, 1) * sfac; \
    const float n0 = pb_ * (a0 + h1); \
    const float n1 = pe4.x * (a1 + a0 + m0 * h1); \
    const float n2 = pb_ * (a2 + a1); \
    const float n3 = pe4.y * (a3 + a2 + m1 * a1); \
    const float n4 = pb_ * (a4 + a3); \
    const float n5 = pe4.z * (a5 + a4 + m2 * a3); \
    const float n6 = pb_ * (a6 + a5); \
    const float n7 = pe4.w * (a7 + a6 + m3 * a5); \
    aX = pb_ * (aX + a7); \
    a0=n0;a1=n1;a2=n2;a3=n3;a4=n4;a5=n5;a6=n6;a7=n7; \
} while (0)

    // Lane-local renorm every 4 steps; zero lanes adopt left exponent (2 rounds,
    // covers front advancing up to 2 lane-boundaries between renorms).
#define RENORM_LOCAL() do { \
    float mm = fmaxf(fmaxf(fmaxf(a0,a1),fmaxf(a2,a3)), fmaxf(fmaxf(a4,a5),fmaxf(a6,a7))); \
    mm = fmaxf(mm, aX); \
    int ee = 0; \
    if (mm > 0.f) { (void)frexpf(mm, &ee); } \
    const float sc = ldexpf(1.f, -ee); \
    a0*=sc;a1*=sc;a2*=sc;a3*=sc;a4*=sc;a5*=sc;a6*=sc;a7*=sc;aX*=sc; \
    Etot += ee; \
    int Ep = __shfl_up(Etot, 1); \
    if (mm == 0.f && lane > 0) Etot = Ep; \
    Ep = __shfl_up(Etot, 1); \
    if (mm == 0.f && lane > 0) Etot = Ep; \
    int dd = Ep - Etot; \
    dd = (dd < -126) ? -126 : ((dd > 100) ? 100 : dd); \
    sfac = ldexpf(lzm, dd); \
} while (0)

    ISSUE(0, 1); ISSUE(1, 9); ISSUE(2, 17);
    int t = 1, slot = 0;
    for (;;) {
        const int ns = (slot + 3) & 3;
        ISSUE(ns, t + 24);                       // keep depth-3 pipeline full (clamped rows)
        WAIT_VM27();                             // oldest chunk (this one) landed in LDS
        __builtin_amdgcn_sched_barrier(0);       // no ds_read may float above the wait
        const float* tcur = tokL[slot];
        const float* bcur = blkL[slot];
        int nv = Tl - t; nv = (nv > 8) ? 8 : nv;
#pragma unroll
        for (int k = 0; k < 8; ++k) {
            if (k < nv) ONESTEP(tcur, bcur, k);
            if (k == 3 || k == 7) RENORM_LOCAL();
        }
        t += 8;
        if (t >= Tl) break;
        slot = (slot + 1) & 3;
    }
    WAIT_VM0();                                  // drain ring before reusing LDS / endpgm

    als[8 * lane + 0] = a0; als[8 * lane + 1] = a1;
    als[8 * lane + 2] = a2; als[8 * lane + 3] = a3;
    als[8 * lane + 4] = a4; als[8 * lane + 5] = a5;
    als[8 * lane + 6] = a6; als[8 * lane + 7] = a7;
    aE[lane] = Etot;
    if (lane == 63) { als[512] = aX; aE[64] = Etot; }
    __syncthreads();
    if (lane == 0) {
        const int sA = 2 * Sl, sB = 2 * Sl - 1;
        const float vA = als[sA], vB = als[sB];
        const int   eA = aE[sA >> 3], eB = aE[sB >> 3];
        int em;
        if (vA > 0.f && vB > 0.f) em = (eA > eB) ? eA : eB;
        else if (vA > 0.f)        em = eA;
        else if (vB > 0.f)        em = eB;
        else                      em = 0;
        const double s = ldexp((double)vA, eA - em) + ldexp((double)vB, eB - em);
        double loss = -(log(s) + (double)em * 0.6931471805599453);
        if (!(loss < 1e29)) loss = 0.0;
        atomicAdd(out, (float)(loss / ((double)Sl * (double)BB)));
    }
#undef ISSUE
#undef ONESTEP
#undef RENORM_LOCAL
}

extern "C" void kernel_launch(void* const* d_in, const int* in_sizes, int n_in,
                              void* d_out, int out_size, void* d_ws, size_t ws_size,
                              hipStream_t stream)
{
    const float* lp     = (const float*)d_in[0];
    const int*   tokens = (const int*)d_in[1];
    const int*   cqt    = (const int*)d_in[2];
    const int*   slen   = (const int*)d_in[3];
    float* out = (float*)d_out;
    float* G   = (float*)d_ws;                          // 32*2048*256 floats = 64 MiB
    float* Gbl = G + (size_t)BB * TT * 256;             // 32*2048 floats + pad (walk reads ahead)

    hipLaunchKernelGGL(ctc_pre,  dim3(BB * (TT / TCHUNK)), dim3(256), 0, stream,
                       lp, tokens, cqt, slen, G, Gbl, out);
    hipLaunchKernelGGL(ctc_walk, dim3(BB), dim3(64), 0, stream,
                       G, Gbl, tokens, cqt, slen, out);
}

// Round 4
// 589.597 us; speedup vs baseline: 1.1289x; 1.0752x over previous
//
#include <hip/hip_runtime.h>
#include <math.h>

#define BB 32
#define TT 2048
#define VV 1024
#define SS 256
#define TCHUNK 4

// ---- async global->LDS: per-lane GLOBAL addr, wave-uniform LDS base + lane*size ----
__device__ __forceinline__ void async_ld16(const float* g, const float* l) {
    __builtin_amdgcn_global_load_lds(
        (const __attribute__((address_space(1))) void*)(uintptr_t)g,
        (__attribute__((address_space(3))) void*)(unsigned)(uintptr_t)l, 16, 0, 0);
}
__device__ __forceinline__ void async_ld4(const float* g, const float* l) {
    __builtin_amdgcn_global_load_lds(
        (const __attribute__((address_space(1))) void*)(uintptr_t)g,
        (__attribute__((address_space(3))) void*)(unsigned)(uintptr_t)l, 4, 0, 0);
}
// s_waitcnt simm16: [3:0]=vmcnt lo, [6:4]=expcnt, [11:8]=lgkmcnt, [15:14]=vmcnt hi
#define WAIT_VM27() __builtin_amdgcn_s_waitcnt(0x4F7B)  // vmcnt<=27
#define WAIT_VM0()  __builtin_amdgcn_s_waitcnt(0x0F70)  // vmcnt<=0

// ---- DPP wave_shr1: value from lane-1, lane0 -> 0. One VALU op, no lgkmcnt. ----
__device__ __forceinline__ float dpp_shr1_f(float x) {
    int r = __builtin_amdgcn_update_dpp(0, __float_as_int(x), 0x138, 0xF, 0xF, true);
    return __int_as_float(r);
}
__device__ __forceinline__ int dpp_shr1_i(int x) {
    return __builtin_amdgcn_update_dpp(0, x, 0x138, 0xF, 0xF, true);
}

// Kernel A: G[b][t][j] = (j<Sl)? exp(lp[b][t][tok_j]) : 0  (row = 256 floats = 64 lanes x 16B)
//           Gbl[b][t]  = exp(lp[b][t][0])  (blank)
__global__ __launch_bounds__(256) void ctc_pre(const float* __restrict__ lp,
    const int* __restrict__ tokens, const int* __restrict__ cqt,
    const int* __restrict__ slen, float* __restrict__ G, float* __restrict__ Gbl,
    float* __restrict__ out)
{
    __shared__ __align__(16) float rows[TCHUNK][VV];
    __shared__ int toks[SS];
    const int tid = threadIdx.x;
    const int bx  = blockIdx.x;
    if (bx == 0 && tid == 0) out[0] = 0.f;   // zero the atomic accumulator (d_out is poisoned)
    const int nchunk = TT / TCHUNK;
    const int b  = bx / nchunk;
    const int t0 = (bx % nchunk) * TCHUNK;
    const int Tl = cqt[b];
    if (t0 >= Tl) return;                    // rows t>=Tl never read by walker
    const int Sl = slen[b];
    toks[tid] = tokens[b * SS + tid];
#pragma unroll
    for (int k = 0; k < TCHUNK; ++k) {       // stage up to 4 rows, one barrier total
        const int t = t0 + k;
        if (t < Tl)
            ((float4*)rows[k])[tid] = ((const float4*)(lp + ((size_t)b * TT + t) * VV))[tid];
    }
    __syncthreads();
#pragma unroll
    for (int k = 0; k < TCHUNK; ++k) {
        const int t = t0 + k;
        if (t >= Tl) break;                  // uniform across block
        float* gp = G + ((size_t)b * TT + t) * 256;
        gp[tid] = (tid < Sl) ? __expf(rows[k][toks[tid]]) : 0.f;
        if (tid == 0) Gbl[b * TT + t] = __expf(rows[k][0]);
    }
}

// Kernel B: serial CTC forward in linear domain, one wave per sample.
// Thread i owns states 8i..8i+7 (pairs j=4i..4i+3: even=blank, odd=token j).
// Per-lane power-of-2 exponent Etot (true = stored * 2^Etot); halo a7 crosses
// lanes via ONE DPP wave_shr1 per step (no ds_bpermute in the serial chain).
// Memory: 4-slot LDS ring filled by async global_load_lds, prefetch depth 3,
// consumed behind explicit s_waitcnt vmcnt(27) (9 vm-ops per chunk, 3 in flight).
__global__ __launch_bounds__(64) void ctc_walk(const float* __restrict__ G,
    const float* __restrict__ Gbl, const int* __restrict__ tokens,
    const int* __restrict__ cqt, const int* __restrict__ slen, float* __restrict__ out)
{
    __shared__ __align__(16) float tokL[4][8 * 256];   // 32 KB: 4 slots x 8 rows x 1KB
    __shared__ __align__(16) float blkL[4][64];        // 1 KB: blank windows
    __shared__ float als[513];
    __shared__ int   aE[65];

    const int b    = blockIdx.x;
    const int lane = threadIdx.x;
    const int Tl   = cqt[b];
    const int Sl   = slen[b];
    const float* __restrict__ Gb   = G   + (size_t)b * TT * 256;
    const float* __restrict__ GblB = Gbl + (size_t)b * TT;
    const int j0 = lane * 4;
    const int* tb = tokens + b * SS;
    const int tm1 = (j0 == 0) ? 0 : tb[j0 - 1];
    const int q0 = tb[j0], q1 = tb[j0 + 1], q2 = tb[j0 + 2], q3 = tb[j0 + 3];
    const float m0 = (q0 != tm1) ? 1.f : 0.f;
    const float m1 = (q1 != q0)  ? 1.f : 0.f;
    const float m2 = (q2 != q1)  ? 1.f : 0.f;
    const float m3 = (q3 != q2)  ? 1.f : 0.f;
    const float lzm = (lane == 0) ? 0.f : 1.f;

    float a0=0.f,a1=0.f,a2=0.f,a3=0.f,a4=0.f,a5=0.f,a6=0.f,a7=0.f,aX=0.f;
    if (lane == 0) { a0 = GblB[0]; a1 = Gb[0]; }   // t=0 init
    int   Etot = 0;
    float sfac = lzm;

    // One chunk = 8 token rows (per-lane gaddr = row + lane*16B) + one blank window
    // (per-lane gaddr = GblB[clamp(tbase+lane)]) = 9 vm ops.
#define ISSUE(slot, tbase) do { \
    const float* lt = tokL[slot]; \
    _Pragma("unroll") \
    for (int k = 0; k < 8; ++k) { \
        int tt = (tbase) + k; tt = (tt < Tl) ? tt : (Tl - 1); \
        async_ld16(Gb + (size_t)tt * 256 + (lane << 2), lt + k * 256); \
    } \
    int tbk = (tbase) + lane; tbk = (tbk < Tl) ? tbk : (Tl - 1); \
    async_ld4(GblB + tbk, blkL[slot]); \
} while (0)

#define ONESTEP(tcur, bcur, k) do { \
    const float4 pe4 = *(const float4*)((tcur) + ((k) << 8) + (lane << 2)); \
    const float pb_ = (bcur)[k]; \
    const float h1 = dpp_shr1_f(a7) * sfac; \
    const float n0 = pb_ * (a0 + h1); \
    const float n1 = pe4.x * (a1 + a0 + m0 * h1); \
    const float n2 = pb_ * (a2 + a1); \
    const float n3 = pe4.y * (a3 + a2 + m1 * a1); \
    const float n4 = pb_ * (a4 + a3); \
    const float n5 = pe4.z * (a5 + a4 + m2 * a3); \
    const float n6 = pb_ * (a6 + a5); \
    const float n7 = pe4.w * (a7 + a6 + m3 * a5); \
    aX = pb_ * (aX + a7); \
    a0=n0;a1=n1;a2=n2;a3=n3;a4=n4;a5=n5;a6=n6;a7=n7; \
} while (0)

    // Lane-local renorm every 4 steps; zero lanes adopt left exponent (2 DPP rounds).
#define RENORM_LOCAL() do { \
    float mm = fmaxf(fmaxf(fmaxf(a0,a1),fmaxf(a2,a3)), fmaxf(fmaxf(a4,a5),fmaxf(a6,a7))); \
    mm = fmaxf(mm, aX); \
    int ee = 0; \
    if (mm > 0.f) { (void)frexpf(mm, &ee); } \
    const float sc = ldexpf(1.f, -ee); \
    a0*=sc;a1*=sc;a2*=sc;a3*=sc;a4*=sc;a5*=sc;a6*=sc;a7*=sc;aX*=sc; \
    Etot += ee; \
    int Ep = dpp_shr1_i(Etot); \
    if (mm == 0.f && lane > 0) Etot = Ep; \
    Ep = dpp_shr1_i(Etot); \
    if (mm == 0.f && lane > 0) Etot = Ep; \
    int dd = Ep - Etot; \
    dd = (dd < -126) ? -126 : ((dd > 100) ? 100 : dd); \
    sfac = ldexpf(lzm, dd); \
} while (0)

    ISSUE(0, 1); ISSUE(1, 9); ISSUE(2, 17);
    int t = 1, slot = 0;
    for (;;) {
        const int ns = (slot + 3) & 3;
        ISSUE(ns, t + 24);                       // keep depth-3 pipeline full (clamped rows)
        WAIT_VM27();                             // oldest chunk (this one) landed in LDS
        __builtin_amdgcn_sched_barrier(0);       // no ds_read may float above the wait
        const float* tcur = tokL[slot];
        const float* bcur = blkL[slot];
        int nv = Tl - t; nv = (nv > 8) ? 8 : nv;
#pragma unroll
        for (int k = 0; k < 8; ++k) {
            if (k < nv) ONESTEP(tcur, bcur, k);
            if (k == 3 || k == 7) RENORM_LOCAL();
        }
        t += 8;
        if (t >= Tl) break;
        slot = (slot + 1) & 3;
    }
    WAIT_VM0();                                  // drain ring before endpgm/epilogue

    als[8 * lane + 0] = a0; als[8 * lane + 1] = a1;
    als[8 * lane + 2] = a2; als[8 * lane + 3] = a3;
    als[8 * lane + 4] = a4; als[8 * lane + 5] = a5;
    als[8 * lane + 6] = a6; als[8 * lane + 7] = a7;
    aE[lane] = Etot;
    if (lane == 63) { als[512] = aX; aE[64] = Etot; }
    __syncthreads();
    if (lane == 0) {
        const int sA = 2 * Sl, sB = 2 * Sl - 1;
        const float vA = als[sA], vB = als[sB];
        const int   eA = aE[sA >> 3], eB = aE[sB >> 3];
        int em;
        if (vA > 0.f && vB > 0.f) em = (eA > eB) ? eA : eB;
        else if (vA > 0.f)        em = eA;
        else if (vB > 0.f)        em = eB;
        else                      em = 0;
        const double s = ldexp((double)vA, eA - em) + ldexp((double)vB, eB - em);
        double loss = -(log(s) + (double)em * 0.6931471805599453);
        if (!(loss < 1e29)) loss = 0.0;
        atomicAdd(out, (float)(loss / ((double)Sl * (double)BB)));
    }
#undef ISSUE
#undef ONESTEP
#undef RENORM_LOCAL
}

extern "C" void kernel_launch(void* const* d_in, const int* in_sizes, int n_in,
                              void* d_out, int out_size, void* d_ws, size_t ws_size,
                              hipStream_t stream)
{
    const float* lp     = (const float*)d_in[0];
    const int*   tokens = (const int*)d_in[1];
    const int*   cqt    = (const int*)d_in[2];
    const int*   slen   = (const int*)d_in[3];
    float* out = (float*)d_out;
    float* G   = (float*)d_ws;                          // 32*2048*256 floats = 64 MiB
    float* Gbl = G + (size_t)BB * TT * 256;             // 32*2048 floats (walk clamps read-ahead)

    hipLaunchKernelGGL(ctc_pre,  dim3(BB * (TT / TCHUNK)), dim3(256), 0, stream,
                       lp, tokens, cqt, slen, G, Gbl, out);
    hipLaunchKernelGGL(ctc_walk, dim3(BB), dim3(64), 0, stream,
                       G, Gbl, tokens, cqt, slen, out);
}